// Round 7
// baseline (165.611 us; speedup 1.0000x reference)
//
#include <hip/hip_runtime.h>
#include <hip/hip_bf16.h>
#include <math.h>

#define D_EMB 1024
#define NBATCH 2
#define SEQ 2048
#define NH 16
#define HDIM 64
#define MTOT (NBATCH*SEQ)   // 4096
#define NT (SEQ/64)         // 32 KV tiles

typedef unsigned short u16;
typedef __attribute__((ext_vector_type(8))) short bf16x8;
typedef __attribute__((ext_vector_type(4))) float f32x4;
typedef __attribute__((ext_vector_type(16))) float f32x16;
typedef __attribute__((ext_vector_type(4))) unsigned short u16x4;
typedef __attribute__((ext_vector_type(4))) unsigned int u32x4;

__device__ __forceinline__ u16 f2b(float f) {
  union { float f; unsigned u; } x; x.f = f;
  unsigned r = x.u + 0x7fffu + ((x.u >> 16) & 1u);
  return (u16)(r >> 16);
}

__device__ __forceinline__ void gld_lds16(const u16* g, u16* l) {
  __builtin_amdgcn_global_load_lds(
      (const __attribute__((address_space(1))) void*)g,
      (__attribute__((address_space(3))) void*)l, 16, 0, 0);
}

// ---------------- convert q,k,v fp32 -> bf16 ----------------
__global__ __launch_bounds__(256) void convert_qkv(
    const float* __restrict__ v, const float* __restrict__ k, const float* __restrict__ q,
    u16* __restrict__ vb, u16* __restrict__ kb, u16* __restrict__ qb) {
  int idx = blockIdx.x * 256 + threadIdx.x;   // float4 units; total 1048576
  float4 a;
  u16x4 o;
  a = ((const float4*)v)[idx];
  o.x = f2b(a.x); o.y = f2b(a.y); o.z = f2b(a.z); o.w = f2b(a.w);
  ((u16x4*)vb)[idx] = o;
  a = ((const float4*)k)[idx];
  o.x = f2b(a.x); o.y = f2b(a.y); o.z = f2b(a.z); o.w = f2b(a.w);
  ((u16x4*)kb)[idx] = o;
  a = ((const float4*)q)[idx];
  o.x = f2b(a.x); o.y = f2b(a.y); o.z = f2b(a.z); o.w = f2b(a.w);
  ((u16x4*)qb)[idx] = o;
}

// ---------------- transpose weights W[k][n] -> Wt[n][k] bf16 ----------------
__global__ __launch_bounds__(256) void transpose_w(
    const float* __restrict__ Wv, const float* __restrict__ Wk,
    const float* __restrict__ Wq, const float* __restrict__ Wo,
    u16* __restrict__ Wvt, u16* __restrict__ Wkt,
    u16* __restrict__ Wqt, u16* __restrict__ Wot) {
  __shared__ float tile[32][33];
  int z = blockIdx.z;
  const float* W = (z==0) ? Wv : (z==1) ? Wk : (z==2) ? Wq : Wo;
  u16* Wt = (z==0) ? Wvt : (z==1) ? Wkt : (z==2) ? Wqt : Wot;
  int tx = threadIdx.x, ty = threadIdx.y;
  int n0 = blockIdx.x * 32, k0 = blockIdx.y * 32;
#pragma unroll
  for (int i = 0; i < 4; ++i)
    tile[ty + i*8][tx] = W[(size_t)(k0 + ty + i*8) * D_EMB + n0 + tx];
  __syncthreads();
#pragma unroll
  for (int i = 0; i < 4; ++i)
    Wt[(size_t)(n0 + ty + i*8) * D_EMB + k0 + tx] = f2b(tile[tx][ty + i*8]);
}

// ---------------- shared GEMM mainloop: C[128x128] tile, K=1024, BK=64 ----------------
__device__ __forceinline__ void gemm_loop(
    const u16* __restrict__ A, const u16* __restrict__ Bt,
    u16* lds_a, u16* lds_b, int bm, int bn, int wid, int lane,
    int wr, int wc, f32x4 acc[4][4]) {
#pragma unroll 1
  for (int kt = 0; kt < D_EMB/64; ++kt) {
    __syncthreads();
#pragma unroll
    for (int i = 0; i < 4; ++i) {
      int chunk = i*4 + wid;                 // 0..15, each = 1KB of LDS
      int row = chunk*8 + (lane >> 3);       // 0..127
      int slot = (lane & 7) ^ (row & 7);     // pre-swizzled source slot
      const u16* srcA = A + (size_t)(bm*128 + row) * D_EMB + kt*64 + slot*8;
      gld_lds16(srcA, lds_a + chunk*512);
      const u16* srcB = Bt + (size_t)(bn*128 + row) * D_EMB + kt*64 + slot*8;
      gld_lds16(srcB, lds_b + chunk*512);
    }
    __syncthreads();
#pragma unroll
    for (int st = 0; st < 2; ++st) {
      bf16x8 af[4], bfr[4];
#pragma unroll
      for (int mb = 0; mb < 4; ++mb) {
        int row = wr*64 + mb*16 + (lane & 15);
        int slot = (st*4 + (lane >> 4)) ^ (row & 7);
        af[mb] = *(const bf16x8*)(lds_a + row*64 + slot*8);
      }
#pragma unroll
      for (int nb = 0; nb < 4; ++nb) {
        int row = wc*64 + nb*16 + (lane & 15);
        int slot = (st*4 + (lane >> 4)) ^ (row & 7);
        bfr[nb] = *(const bf16x8*)(lds_b + row*64 + slot*8);
      }
#pragma unroll
      for (int mb = 0; mb < 4; ++mb)
#pragma unroll
        for (int nb = 0; nb < 4; ++nb)
          acc[mb][nb] = __builtin_amdgcn_mfma_f32_16x16x32_bf16(af[mb], bfr[nb], acc[mb][nb], 0, 0, 0);
    }
  }
}

// ---------------- QKV projection GEMMs (z: 0=V,1=K,2=Q) ----------------
__global__ __launch_bounds__(256) void gemm_qkv(
    const u16* __restrict__ vb, const u16* __restrict__ kb, const u16* __restrict__ qb,
    const u16* __restrict__ Wvt, const u16* __restrict__ Wkt, const u16* __restrict__ Wqt,
    const float* __restrict__ bv, const float* __restrict__ bk, const float* __restrict__ bq,
    u16* __restrict__ Vt, u16* __restrict__ Kh, u16* __restrict__ Qh) {
  __shared__ u16 lds_a[128*64];
  __shared__ u16 lds_b[128*64];
  int z = blockIdx.z;
  const u16* A  = (z==0) ? vb : (z==1) ? kb : qb;
  const u16* Bt = (z==0) ? Wvt : (z==1) ? Wkt : Wqt;
  const float* bias = (z==0) ? bv : (z==1) ? bk : bq;
  int tid = threadIdx.x, wid = tid >> 6, lane = tid & 63;
  int wr = wid >> 1, wc = wid & 1;
  int bm = blockIdx.y, bn = blockIdx.x;
  f32x4 acc[4][4];
#pragma unroll
  for (int i = 0; i < 4; ++i)
#pragma unroll
    for (int j = 0; j < 4; ++j) acc[i][j] = (f32x4){0.f,0.f,0.f,0.f};
  gemm_loop(A, Bt, lds_a, lds_b, bm, bn, wid, lane, wr, wc, acc);
  int g = lane >> 4, c = lane & 15;
#pragma unroll
  for (int mb = 0; mb < 4; ++mb) {
    int row0 = bm*128 + wr*64 + mb*16 + g*4;
#pragma unroll
    for (int nb = 0; nb < 4; ++nb) {
      int col = bn*128 + wc*64 + nb*16 + c;
      float bsv = bias[col];
      int h = col >> 6, dd = col & 63;
      if (z == 2) {
#pragma unroll
        for (int r = 0; r < 4; ++r) {
          int m = row0 + r; int b = m >> 11, s = m & (SEQ-1);
          // fold 1/sqrt(64) * log2(e): softmax runs in exp2 domain
          float val = (acc[mb][nb][r] + bsv) * 0.18033688f;
          Qh[(((size_t)b*NH + h)*SEQ + s)*HDIM + dd] = f2b(val);
        }
      } else if (z == 1) {
#pragma unroll
        for (int r = 0; r < 4; ++r) {
          int m = row0 + r; int b = m >> 11, s = m & (SEQ-1);
          Kh[(((size_t)b*NH + h)*SEQ + s)*HDIM + dd] = f2b(acc[mb][nb][r] + bsv);
        }
      } else {
        int m = row0; int b = m >> 11, s = m & (SEQ-1);
        u16x4 pk;
        pk.x = f2b(acc[mb][nb][0] + bsv);
        pk.y = f2b(acc[mb][nb][1] + bsv);
        pk.z = f2b(acc[mb][nb][2] + bsv);
        pk.w = f2b(acc[mb][nb][3] + bsv);
        *(u16x4*)(Vt + (((size_t)b*NH + h)*HDIM + dd)*SEQ + s) = pk;
      }
    }
  }
}

// ---------------- flash attention, rotated 4-buffer pipeline ----------------
// 4 waves x 32 q-rows = 128 q/block; grid (16, 32) = 512 blocks = 2/CU.
// KVBLK=64. 4 LDS buffers (64KB/block), stage 3 tiles ahead, ONE barrier/tile.
// Frag reads for K(t+1),V(t) issue right after the barrier and drain under
// cvt+PV(t); QK^T(t) finds operands pre-loaded (lgkmcnt covered by PV(t-1)).
// vmcnt(4) counted (stage t+2 stays in flight); vmcnt(0) only at t=NT-2.
// LDS swizzle: physical slot p = chunk ^ (row&7) ^ (row>>3) -> conflict-free.
__global__ __launch_bounds__(256, 2) void attn_k(
    const u16* __restrict__ Qh, const u16* __restrict__ Kh,
    const u16* __restrict__ Vt, u16* __restrict__ ctx) {
  __shared__ u16 kt_lds[4][64*64];   // 4 x 8KB
  __shared__ u16 vt_lds[4][64*64];   // 4 x 8KB
  const int tid = threadIdx.x, wid = tid >> 6, lane = tid & 63;
  const int lo5 = lane & 31, hi = lane >> 5;
  const int bh = blockIdx.y;
  const int qb = blockIdx.x * 128 + wid * 32;
  const size_t base = (size_t)bh * SEQ * HDIM;

  // staging source (pre-swizzled): physical cell (row,p) holds chunk
  // c = p ^ (row&7) ^ (row>>3)
  const int srow = tid >> 3;                       // 0..31
  const int c0 = (tid & 7) ^ (srow & 7) ^ (srow >> 3);
  const int c1 = c0 ^ 4;                           // rows +32: row>>3 ^= 4
  const u16* kp0 = Kh + base + (size_t)srow * HDIM + c0*8;
  const u16* kp1 = Kh + base + (size_t)(srow+32) * HDIM + c1*8;
  const u16* vp0 = Vt + base + (size_t)srow * SEQ + c0*8;
  const u16* vp1 = Vt + base + (size_t)(srow+32) * SEQ + c1*8;

  // per-lane LDS read byte-offsets (computed once; loop uses imm offsets only)
  const int r7 = lo5 & 7, r3 = lo5 >> 3;           // r3 in 0..3
  int offs0[4], offs1[4];
#pragma unroll
  for (int t = 0; t < 4; ++t) {
    int p = (2*t + hi) ^ r7 ^ r3;
    offs0[t] = lo5*128 + p*16;
    offs1[t] = (lo5+32)*128 + (p^4)*16;
  }
  const char* ktbase = (const char*)&kt_lds[0][0];
  const char* vtbase = (const char*)&vt_lds[0][0];

  // Q B-fragments (lane holds Q[q=lo5][d=t*16+hi*8+j]); Q pre-scaled
  bf16x8 qf[4];
#pragma unroll
  for (int t = 0; t < 4; ++t)
    qf[t] = *(const bf16x8*)(Qh + base + (size_t)(qb + lo5)*HDIM + t*16 + hi*8);

  // ones B-frag for l row-sums via MFMA
  bf16x8 onesf;
#pragma unroll
  for (int j = 0; j < 8; ++j) onesf[j] = (short)0x3F80;
  f32x16 z16;
#pragma unroll
  for (int i = 0; i < 16; ++i) z16[i] = 0.f;

  f32x16 o0, o1, lacc;
#pragma unroll
  for (int i = 0; i < 16; ++i) { o0[i] = 0.f; o1[i] = 0.f; lacc[i] = 0.f; }
  float m = -1e30f;
  const float THR = 11.5f;   // 8 * log2(e)

  bf16x8 kf0[4], kf1[4];   // K frags of current tile (reloaded each tile)
  bf16x8 vf0[4], vf1[4];   // V frags of current tile

#define STAGE(B) do { \
    gld_lds16(kp0, &kt_lds[B][wid*512]); \
    gld_lds16(kp1, &kt_lds[B][2048 + wid*512]); \
    gld_lds16(vp0, &vt_lds[B][wid*512]); \
    gld_lds16(vp1, &vt_lds[B][2048 + wid*512]); \
    kp0 += 64*HDIM; kp1 += 64*HDIM; vp0 += 64; vp1 += 64; \
  } while (0)

#define READK(B) do { \
    const char* kb_ = ktbase + (B)*8192; \
    _Pragma("unroll") for (int t = 0; t < 4; ++t) { \
      kf0[t] = *(const bf16x8*)(kb_ + offs0[t]); \
      kf1[t] = *(const bf16x8*)(kb_ + offs1[t]); } \
  } while (0)

#define READV(B) do { \
    const char* vb_ = vtbase + (B)*8192; \
    _Pragma("unroll") for (int t = 0; t < 4; ++t) { \
      vf0[t] = *(const bf16x8*)(vb_ + offs0[t]); \
      vf1[t] = *(const bf16x8*)(vb_ + offs1[t]); } \
  } while (0)

#define QKT_SM() \
    __builtin_amdgcn_s_setprio(1); \
    f32x16 st0 = __builtin_amdgcn_mfma_f32_32x32x16_bf16(kf0[0], qf[0], z16, 0, 0, 0); \
    f32x16 st1 = __builtin_amdgcn_mfma_f32_32x32x16_bf16(kf1[0], qf[0], z16, 0, 0, 0); \
    _Pragma("unroll") for (int t = 1; t < 4; ++t) { \
      st0 = __builtin_amdgcn_mfma_f32_32x32x16_bf16(kf0[t], qf[t], st0, 0, 0, 0); \
      st1 = __builtin_amdgcn_mfma_f32_32x32x16_bf16(kf1[t], qf[t], st1, 0, 0, 0); } \
    __builtin_amdgcn_s_setprio(0); \
    float pm = fmaxf(st0[0], st1[0]); \
    _Pragma("unroll") for (int r = 1; r < 16; ++r) \
      pm = fmaxf(pm, fmaxf(st0[r], st1[r])); \
    pm = fmaxf(pm, __shfl_xor(pm, 32)); \
    if (__any(pm > m + THR)) { \
      float mn = fmaxf(m, pm); \
      float scl = exp2f(m - mn); \
      m = mn; \
      _Pragma("unroll") for (int r = 0; r < 16; ++r) { \
        int crow = (r & 3) + 8*(r >> 2) + 4*hi; \
        float sr = __int_as_float( \
            __builtin_amdgcn_ds_bpermute(crow << 2, __float_as_int(scl))); \
        o0[r] *= sr; o1[r] *= sr; lacc[r] *= sr; } } \
    _Pragma("unroll") for (int r = 0; r < 16; ++r) st0[r] = exp2f(st0[r] - m); \
    _Pragma("unroll") for (int r = 0; r < 16; ++r) st1[r] = exp2f(st1[r] - m);

#define CVT_PA() \
    bf16x8 pa[4]; \
    _Pragma("unroll") for (int ks = 0; ks < 2; ++ks) { \
      const f32x16& s_ = ks ? st1 : st0; \
      unsigned X[8]; \
      _Pragma("unroll") for (int w = 0; w < 8; ++w) { \
        float lo_f = s_[2*w], hi_f = s_[2*w + 1]; \
        asm("v_cvt_pk_bf16_f32 %0, %1, %2" : "=v"(X[w]) : "v"(lo_f), "v"(hi_f)); } \
      asm volatile("v_permlane32_swap_b32 %0, %1" : "+v"(X[0]), "+v"(X[2])); \
      asm volatile("v_permlane32_swap_b32 %0, %1" : "+v"(X[1]), "+v"(X[3])); \
      asm volatile("v_permlane32_swap_b32 %0, %1" : "+v"(X[4]), "+v"(X[6])); \
      asm volatile("v_permlane32_swap_b32 %0, %1" : "+v"(X[5]), "+v"(X[7])); \
      union { u32x4 u; bf16x8 b; } cva, cvb; \
      cva.u = (u32x4){X[0], X[1], X[2], X[3]}; \
      cvb.u = (u32x4){X[4], X[5], X[6], X[7]}; \
      pa[2*ks]   = cva.b; \
      pa[2*ks+1] = cvb.b; }

#define PV() \
    __builtin_amdgcn_s_setprio(1); \
    _Pragma("unroll") for (int t = 0; t < 4; ++t) { \
      o0 = __builtin_amdgcn_mfma_f32_32x32x16_bf16(pa[t], vf0[t], o0, 0, 0, 0); \
      o1 = __builtin_amdgcn_mfma_f32_32x32x16_bf16(pa[t], vf1[t], o1, 0, 0, 0); } \
    _Pragma("unroll") for (int t = 0; t < 4; ++t) \
      lacc = __builtin_amdgcn_mfma_f32_32x32x16_bf16(pa[t], onesf, lacc, 0, 0, 0); \
    __builtin_amdgcn_s_setprio(0);

// One pipelined tile. B = t&3. VMSTR: "vmcnt(4)" steady / "vmcnt(0)" at NT-2.
// DOSTAGE stages tile t+3 into buf SB=(t+3)&3. Always reads V(t) and K(t+1).
#define TILE(B, VMSTR, DOSTAGE, SB) do { \
    asm volatile("s_waitcnt lgkmcnt(0)" ::: "memory");   /* kf = K(t) ready */ \
    __builtin_amdgcn_sched_barrier(0); \
    QKT_SM() \
    asm volatile("s_waitcnt " VMSTR ::: "memory");       /* stage(t+1) landed */ \
    __builtin_amdgcn_sched_barrier(0); \
    __builtin_amdgcn_s_barrier(); \
    __builtin_amdgcn_sched_barrier(0); \
    if (DOSTAGE) { STAGE(SB); } \
    READV(B);                 /* V(t): 8 ds_read */ \
    READK((B+1)&3);           /* K(t+1): 8 ds_read */ \
    CVT_PA()                  /* VALU overlaps LDS drain */ \
    asm volatile("s_waitcnt lgkmcnt(8)" ::: "memory");   /* V(t) done, K(t+1) in flight */ \
    __builtin_amdgcn_sched_barrier(0); \
    PV() \
  } while (0)

  // prologue: stage tiles 0,1,2 (12 loads); wait tile 0; preload K(0)
  STAGE(0); STAGE(1); STAGE(2);
  asm volatile("s_waitcnt vmcnt(8)" ::: "memory");
  __builtin_amdgcn_sched_barrier(0);
  __builtin_amdgcn_s_barrier();
  __builtin_amdgcn_sched_barrier(0);
  READK(0);

#pragma unroll 1
  for (int kv = 0; kv < NT - 4; kv += 4) {
    TILE(0, "vmcnt(4)", 1, 3);
    TILE(1, "vmcnt(4)", 1, 0);
    TILE(2, "vmcnt(4)", 1, 1);
    TILE(3, "vmcnt(4)", 1, 2);
  }
  TILE(0, "vmcnt(4)", 1, 3);     // t=28, stages tile 31
  TILE(1, "vmcnt(4)", 0, 0);     // t=29
  TILE(2, "vmcnt(0)", 0, 0);     // t=30 (drain: tile 31 landed)
  // t=31 final: no barrier/stage; V(31) in buf3, K(31) preloaded by t=30
  {
    asm volatile("s_waitcnt lgkmcnt(0)" ::: "memory");
    __builtin_amdgcn_sched_barrier(0);
    QKT_SM()
    READV(3);
    CVT_PA()
    asm volatile("s_waitcnt lgkmcnt(0)" ::: "memory");
    __builtin_amdgcn_sched_barrier(0);
    PV()
  }

#undef STAGE
#undef READK
#undef READV
#undef QKT_SM
#undef CVT_PA
#undef PV
#undef TILE

  // ---- epilogue: O /= l (l already in C layout via MFMA row-sum) ----
  const int b = bh >> 4, h = bh & 15;
#pragma unroll
  for (int r = 0; r < 16; ++r) {
    int crow = (r & 3) + 8*(r >> 2) + 4*hi;
    float lr = 1.0f / lacc[r];
    int s = qb + crow;
    u16* row = ctx + ((size_t)(b*SEQ + s))*D_EMB + h*64;
    row[lo5]      = f2b(o0[r] * lr);
    row[32 + lo5] = f2b(o1[r] * lr);
  }
}

// ---------------- output projection + bias + residual ----------------
__global__ __launch_bounds__(256) void gemm_out(
    const u16* __restrict__ ctx, const u16* __restrict__ Wot,
    const float* __restrict__ bo, const float* __restrict__ resid,
    float* __restrict__ preln) {
  __shared__ u16 lds_a[128*64];
  __shared__ u16 lds_b[128*64];
  int tid = threadIdx.x, wid = tid >> 6, lane = tid & 63;
  int wr = wid >> 1, wc = wid & 1;
  int bm = blockIdx.y, bn = blockIdx.x;
  f32x4 acc[4][4];
#pragma unroll
  for (int i = 0; i < 4; ++i)
#pragma unroll
    for (int j = 0; j < 4; ++j) acc[i][j] = (f32x4){0.f,0.f,0.f,0.f};
  gemm_loop(ctx, Wot, lds_a, lds_b, bm, bn, wid, lane, wr, wc, acc);
  int g = lane >> 4, c = lane & 15;
#pragma unroll
  for (int mb = 0; mb < 4; ++mb) {
    int row0 = bm*128 + wr*64 + mb*16 + g*4;
#pragma unroll
    for (int nb = 0; nb < 4; ++nb) {
      int col = bn*128 + wc*64 + nb*16 + c;
      float bsv = bo[col];
#pragma unroll
      for (int r = 0; r < 4; ++r) {
        int m = row0 + r;
        preln[(size_t)m*D_EMB + col] = acc[mb][nb][r] + bsv + resid[(size_t)m*D_EMB + col];
      }
    }
  }
}

// ---------------- LayerNorm over rows of 1024 ----------------
__global__ __launch_bounds__(256) void ln_k(
    const float* __restrict__ preln, const float* __restrict__ gamma,
    const float* __restrict__ beta, float* __restrict__ out) {
  int row = blockIdx.x, tid = threadIdx.x;
  float4 x = ((const float4*)(preln + (size_t)row*D_EMB))[tid];
  float s  = x.x + x.y + x.z + x.w;
  float ss = x.x*x.x + x.y*x.y + x.z*x.z + x.w*x.w;
#pragma unroll
  for (int off = 32; off; off >>= 1) {
    s  += __shfl_xor(s, off);
    ss += __shfl_xor(ss, off);
  }
  __shared__ float red_s[4], red_ss[4];
  int wid = tid >> 6, lane = tid & 63;
  if (lane == 0) { red_s[wid] = s; red_ss[wid] = ss; }
  __syncthreads();
  s  = red_s[0] + red_s[1] + red_s[2] + red_s[3];
  ss = red_ss[0] + red_ss[1] + red_ss[2] + red_ss[3];
  float mu = s * (1.0f/1024.0f);
  float var = ss * (1.0f/1024.0f) - mu*mu;
  float rstd = rsqrtf(var + 1e-6f);
  float4 gm = ((const float4*)gamma)[tid];
  float4 bt = ((const float4*)beta)[tid];
  float4 y;
  y.x = (x.x - mu)*rstd*gm.x + bt.x;
  y.y = (x.y - mu)*rstd*gm.y + bt.y;
  y.z = (x.z - mu)*rstd*gm.z + bt.z;
  y.w = (x.w - mu)*rstd*gm.w + bt.w;
  ((float4*)(out + (size_t)row*D_EMB))[tid] = y;
}

extern "C" void kernel_launch(void* const* d_in, const int* in_sizes, int n_in,
                              void* d_out, int out_size, void* d_ws, size_t ws_size,
                              hipStream_t stream) {
  const float* v_in  = (const float*)d_in[0];
  const float* k_in  = (const float*)d_in[1];
  const float* q_in  = (const float*)d_in[2];
  const float* Wv    = (const float*)d_in[3];
  const float* bv    = (const float*)d_in[4];
  const float* Wk    = (const float*)d_in[5];
  const float* bk    = (const float*)d_in[6];
  const float* Wq    = (const float*)d_in[7];
  const float* bq    = (const float*)d_in[8];
  const float* Wo    = (const float*)d_in[9];
  const float* bo    = (const float*)d_in[10];
  const float* gamma = (const float*)d_in[11];
  const float* beta  = (const float*)d_in[12];
  char* ws = (char*)d_ws;

  const size_t TOKB = (size_t)MTOT * D_EMB * 2;   // bf16 activation (8 MB)
  const size_t WB   = (size_t)D_EMB * D_EMB * 2;  // bf16 weight (2 MB)
  size_t o_qb = 0;
  size_t o_kb = o_qb + TOKB;
  size_t o_vb = o_kb + TOKB;
  size_t o_wq = o_vb + TOKB;
  size_t o_wk = o_wq + WB;
  size_t o_wv = o_wk + WB;
  size_t o_wo = o_wv + WB;
  size_t o_Qh = o_wo + WB;
  size_t o_Kh = o_Qh + TOKB;
  size_t o_Vt = o_Kh + TOKB;
  size_t o_cx = o_Vt + TOKB;
  // preln (fp32, 16 MB) aliases qb+kb, which are dead after gemm_qkv

  u16* qb  = (u16*)(ws + o_qb);
  u16* kb  = (u16*)(ws + o_kb);
  u16* vb  = (u16*)(ws + o_vb);
  u16* wqt = (u16*)(ws + o_wq);
  u16* wkt = (u16*)(ws + o_wk);
  u16* wvt = (u16*)(ws + o_wv);
  u16* wot = (u16*)(ws + o_wo);
  u16* Qh  = (u16*)(ws + o_Qh);
  u16* Kh  = (u16*)(ws + o_Kh);
  u16* Vt  = (u16*)(ws + o_Vt);
  u16* cx  = (u16*)(ws + o_cx);
  float* preln = (float*)(ws + 0);

  convert_qkv<<<4096, 256, 0, stream>>>(v_in, k_in, q_in, vb, kb, qb);
  transpose_w<<<dim3(32, 32, 4), dim3(32, 8), 0, stream>>>(Wv, Wk, Wq, Wo, wvt, wkt, wqt, wot);
  gemm_qkv<<<dim3(8, 32, 3), 256, 0, stream>>>(vb, kb, qb, wvt, wkt, wqt, bv, bk, bq, Vt, Kh, Qh);
  attn_k<<<dim3(16, 32), 256, 0, stream>>>(Qh, Kh, Vt, cx);
  gemm_out<<<dim3(8, 32), 256, 0, stream>>>(cx, wot, bo, q_in, preln);
  ln_k<<<4096, 256, 0, stream>>>(preln, gamma, beta, (float*)d_out);
}

// Round 8
// 158.199 us; speedup vs baseline: 1.0469x; 1.0469x over previous
//
#include <hip/hip_runtime.h>
#include <hip/hip_bf16.h>
#include <math.h>

#define D_EMB 1024
#define NBATCH 2
#define SEQ 2048
#define NH 16
#define HDIM 64
#define MTOT (NBATCH*SEQ)   // 4096
#define NT (SEQ/64)         // 32 KV tiles

typedef unsigned short u16;
typedef __attribute__((ext_vector_type(8))) short bf16x8;
typedef __attribute__((ext_vector_type(4))) float f32x4;
typedef __attribute__((ext_vector_type(16))) float f32x16;
typedef __attribute__((ext_vector_type(4))) unsigned short u16x4;
typedef __attribute__((ext_vector_type(4))) unsigned int u32x4;

__device__ __forceinline__ u16 f2b(float f) {
  union { float f; unsigned u; } x; x.f = f;
  unsigned r = x.u + 0x7fffu + ((x.u >> 16) & 1u);
  return (u16)(r >> 16);
}

__device__ __forceinline__ void gld_lds16(const u16* g, u16* l) {
  __builtin_amdgcn_global_load_lds(
      (const __attribute__((address_space(1))) void*)g,
      (__attribute__((address_space(3))) void*)l, 16, 0, 0);
}

// ---------------- convert q,k,v fp32 -> bf16 ----------------
__global__ __launch_bounds__(256) void convert_qkv(
    const float* __restrict__ v, const float* __restrict__ k, const float* __restrict__ q,
    u16* __restrict__ vb, u16* __restrict__ kb, u16* __restrict__ qb) {
  int idx = blockIdx.x * 256 + threadIdx.x;   // float4 units; total 1048576
  float4 a;
  u16x4 o;
  a = ((const float4*)v)[idx];
  o.x = f2b(a.x); o.y = f2b(a.y); o.z = f2b(a.z); o.w = f2b(a.w);
  ((u16x4*)vb)[idx] = o;
  a = ((const float4*)k)[idx];
  o.x = f2b(a.x); o.y = f2b(a.y); o.z = f2b(a.z); o.w = f2b(a.w);
  ((u16x4*)kb)[idx] = o;
  a = ((const float4*)q)[idx];
  o.x = f2b(a.x); o.y = f2b(a.y); o.z = f2b(a.z); o.w = f2b(a.w);
  ((u16x4*)qb)[idx] = o;
}

// ---------------- transpose weights W[k][n] -> Wt[n][k] bf16 ----------------
__global__ __launch_bounds__(256) void transpose_w(
    const float* __restrict__ Wv, const float* __restrict__ Wk,
    const float* __restrict__ Wq, const float* __restrict__ Wo,
    u16* __restrict__ Wvt, u16* __restrict__ Wkt,
    u16* __restrict__ Wqt, u16* __restrict__ Wot) {
  __shared__ float tile[32][33];
  int z = blockIdx.z;
  const float* W = (z==0) ? Wv : (z==1) ? Wk : (z==2) ? Wq : Wo;
  u16* Wt = (z==0) ? Wvt : (z==1) ? Wkt : (z==2) ? Wqt : Wot;
  int tx = threadIdx.x, ty = threadIdx.y;
  int n0 = blockIdx.x * 32, k0 = blockIdx.y * 32;
#pragma unroll
  for (int i = 0; i < 4; ++i)
    tile[ty + i*8][tx] = W[(size_t)(k0 + ty + i*8) * D_EMB + n0 + tx];
  __syncthreads();
#pragma unroll
  for (int i = 0; i < 4; ++i)
    Wt[(size_t)(n0 + ty + i*8) * D_EMB + k0 + tx] = f2b(tile[tx][ty + i*8]);
}

// ---------------- shared GEMM mainloop: C[128x128] tile, K=1024, BK=64 ----------------
__device__ __forceinline__ void gemm_loop(
    const u16* __restrict__ A, const u16* __restrict__ Bt,
    u16* lds_a, u16* lds_b, int bm, int bn, int wid, int lane,
    int wr, int wc, f32x4 acc[4][4]) {
#pragma unroll 1
  for (int kt = 0; kt < D_EMB/64; ++kt) {
    __syncthreads();
#pragma unroll
    for (int i = 0; i < 4; ++i) {
      int chunk = i*4 + wid;                 // 0..15, each = 1KB of LDS
      int row = chunk*8 + (lane >> 3);       // 0..127
      int slot = (lane & 7) ^ (row & 7);     // pre-swizzled source slot
      const u16* srcA = A + (size_t)(bm*128 + row) * D_EMB + kt*64 + slot*8;
      gld_lds16(srcA, lds_a + chunk*512);
      const u16* srcB = Bt + (size_t)(bn*128 + row) * D_EMB + kt*64 + slot*8;
      gld_lds16(srcB, lds_b + chunk*512);
    }
    __syncthreads();
#pragma unroll
    for (int st = 0; st < 2; ++st) {
      bf16x8 af[4], bfr[4];
#pragma unroll
      for (int mb = 0; mb < 4; ++mb) {
        int row = wr*64 + mb*16 + (lane & 15);
        int slot = (st*4 + (lane >> 4)) ^ (row & 7);
        af[mb] = *(const bf16x8*)(lds_a + row*64 + slot*8);
      }
#pragma unroll
      for (int nb = 0; nb < 4; ++nb) {
        int row = wc*64 + nb*16 + (lane & 15);
        int slot = (st*4 + (lane >> 4)) ^ (row & 7);
        bfr[nb] = *(const bf16x8*)(lds_b + row*64 + slot*8);
      }
#pragma unroll
      for (int mb = 0; mb < 4; ++mb)
#pragma unroll
        for (int nb = 0; nb < 4; ++nb)
          acc[mb][nb] = __builtin_amdgcn_mfma_f32_16x16x32_bf16(af[mb], bfr[nb], acc[mb][nb], 0, 0, 0);
    }
  }
}

// ---------------- QKV projection GEMMs (z: 0=V,1=K,2=Q) ----------------
__global__ __launch_bounds__(256) void gemm_qkv(
    const u16* __restrict__ vb, const u16* __restrict__ kb, const u16* __restrict__ qb,
    const u16* __restrict__ Wvt, const u16* __restrict__ Wkt, const u16* __restrict__ Wqt,
    const float* __restrict__ bv, const float* __restrict__ bk, const float* __restrict__ bq,
    u16* __restrict__ Vt, u16* __restrict__ Kh, u16* __restrict__ Qh) {
  __shared__ u16 lds_a[128*64];
  __shared__ u16 lds_b[128*64];
  int z = blockIdx.z;
  const u16* A  = (z==0) ? vb : (z==1) ? kb : qb;
  const u16* Bt = (z==0) ? Wvt : (z==1) ? Wkt : Wqt;
  const float* bias = (z==0) ? bv : (z==1) ? bk : bq;
  int tid = threadIdx.x, wid = tid >> 6, lane = tid & 63;
  int wr = wid >> 1, wc = wid & 1;
  int bm = blockIdx.y, bn = blockIdx.x;
  f32x4 acc[4][4];
#pragma unroll
  for (int i = 0; i < 4; ++i)
#pragma unroll
    for (int j = 0; j < 4; ++j) acc[i][j] = (f32x4){0.f,0.f,0.f,0.f};
  gemm_loop(A, Bt, lds_a, lds_b, bm, bn, wid, lane, wr, wc, acc);
  int g = lane >> 4, c = lane & 15;
#pragma unroll
  for (int mb = 0; mb < 4; ++mb) {
    int row0 = bm*128 + wr*64 + mb*16 + g*4;
#pragma unroll
    for (int nb = 0; nb < 4; ++nb) {
      int col = bn*128 + wc*64 + nb*16 + c;
      float bsv = bias[col];
      int h = col >> 6, dd = col & 63;
      if (z == 2) {
#pragma unroll
        for (int r = 0; r < 4; ++r) {
          int m = row0 + r; int b = m >> 11, s = m & (SEQ-1);
          // fold 1/sqrt(64) * log2(e): softmax runs in exp2 domain
          float val = (acc[mb][nb][r] + bsv) * 0.18033688f;
          Qh[(((size_t)b*NH + h)*SEQ + s)*HDIM + dd] = f2b(val);
        }
      } else if (z == 1) {
#pragma unroll
        for (int r = 0; r < 4; ++r) {
          int m = row0 + r; int b = m >> 11, s = m & (SEQ-1);
          Kh[(((size_t)b*NH + h)*SEQ + s)*HDIM + dd] = f2b(acc[mb][nb][r] + bsv);
        }
      } else {
        int m = row0; int b = m >> 11, s = m & (SEQ-1);
        u16x4 pk;
        pk.x = f2b(acc[mb][nb][0] + bsv);
        pk.y = f2b(acc[mb][nb][1] + bsv);
        pk.z = f2b(acc[mb][nb][2] + bsv);
        pk.w = f2b(acc[mb][nb][3] + bsv);
        *(u16x4*)(Vt + (((size_t)b*NH + h)*HDIM + dd)*SEQ + s) = pk;
      }
    }
  }
}

// ---------------- flash attention, 32x32 swapped-QK^T, in-register softmax ----
// R6 structure (counted-vmcnt dbuf) + T1 XCD-aware block swizzle:
// grid = 512 1D; XCD (bid&7) hosts only bh in {x, 8+x, 16+x, 24+x} -> the 64
// concurrent blocks on one XCD touch 4 bh x 512KB = 2MB K/V < 4MB L2.
// K/V then HBM-fetched once and L2-served (latency ~200cy not ~900cy).
__global__ __launch_bounds__(256, 2) void attn_k(
    const u16* __restrict__ Qh, const u16* __restrict__ Kh,
    const u16* __restrict__ Vt, u16* __restrict__ ctx) {
  __shared__ u16 kt_lds[2][64*64];   // [buf][row][8 slots x 8 u16] swizzled
  __shared__ u16 vt_lds[2][64*64];
  const int tid = threadIdx.x, wid = tid >> 6, lane = tid & 63;
  const int lo5 = lane & 31, hi = lane >> 5;
  // XCD swizzle: bid -> (qblk, bh) with bh ≡ (bid&7) mod 8
  const int bid = blockIdx.x;
  const int xcd = bid & 7, idx = bid >> 3;     // idx 0..63 per XCD
  const int qblk = idx & 15, bhg = idx >> 4;   // 16 qblks, 4 bh-groups
  const int bh = bhg * 8 + xcd;
  const int qb = qblk * 128 + wid * 32;
  const size_t base = (size_t)bh * SEQ * HDIM;

  // staging source (pre-swizzled): physical cell (row,p) holds chunk
  // c = p ^ (row&7) ^ (row>>3)
  const int srow = tid >> 3;                       // 0..31
  const int c0 = (tid & 7) ^ (srow & 7) ^ (srow >> 3);
  const int c1 = c0 ^ 4;                           // rows +32: row>>3 ^= 4
  const u16* kp0 = Kh + base + (size_t)srow * HDIM + c0*8;
  const u16* kp1 = Kh + base + (size_t)(srow+32) * HDIM + c1*8;
  const u16* vp0 = Vt + base + (size_t)srow * SEQ + c0*8;
  const u16* vp1 = Vt + base + (size_t)(srow+32) * SEQ + c1*8;

  // per-lane LDS read byte-offsets (computed once; loop uses imm offsets only)
  const int r7 = lo5 & 7, r3 = lo5 >> 3;           // r3 in 0..3
  int offs0[4], offs1[4];
#pragma unroll
  for (int t = 0; t < 4; ++t) {
    int p = (2*t + hi) ^ r7 ^ r3;
    offs0[t] = lo5*128 + p*16;
    offs1[t] = (lo5+32)*128 + (p^4)*16;
  }
  const char* ktbase = (const char*)&kt_lds[0][0];
  const char* vtbase = (const char*)&vt_lds[0][0];

  // Q B-fragments (lane holds Q[q=lo5][d=t*16+hi*8+j]); Q pre-scaled
  bf16x8 qf[4];
#pragma unroll
  for (int t = 0; t < 4; ++t)
    qf[t] = *(const bf16x8*)(Qh + base + (size_t)(qb + lo5)*HDIM + t*16 + hi*8);

  // ones B-frag for l row-sums via MFMA
  bf16x8 onesf;
#pragma unroll
  for (int j = 0; j < 8; ++j) onesf[j] = (short)0x3F80;
  f32x16 z16;
#pragma unroll
  for (int i = 0; i < 16; ++i) z16[i] = 0.f;

  f32x16 o0, o1, lacc;
#pragma unroll
  for (int i = 0; i < 16; ++i) { o0[i] = 0.f; o1[i] = 0.f; lacc[i] = 0.f; }
  float m = -1e30f;
  const float THR = 11.5f;   // 8 * log2(e)

#define STAGE(B) do { \
    gld_lds16(kp0, &kt_lds[B][wid*512]); \
    gld_lds16(kp1, &kt_lds[B][2048 + wid*512]); \
    gld_lds16(vp0, &vt_lds[B][wid*512]); \
    gld_lds16(vp1, &vt_lds[B][2048 + wid*512]); \
    kp0 += 64*HDIM; kp1 += 64*HDIM; vp0 += 64; vp1 += 64; \
  } while (0)

// One KV tile, counted-vmcnt pipeline.
//   VMSTR: "vmcnt(4)" in steady state (next tile's 4 loads stay in flight),
//          "vmcnt(0)" only for the last tile.
//   DOSTAGE: stage tile t+2 into this buffer right after it's been read.
#define TILE(B, VMSTR, DOSTAGE) do { \
    asm volatile("s_waitcnt " VMSTR ::: "memory"); \
    __builtin_amdgcn_sched_barrier(0); \
    __builtin_amdgcn_s_barrier();            /* tile t in LDS for all waves */ \
    __builtin_amdgcn_sched_barrier(0); \
    const char* kb_ = ktbase + (B)*8192; \
    const char* vb_ = vtbase + (B)*8192; \
    bf16x8 kf0[4], kf1[4], vf0[4], vf1[4]; \
    _Pragma("unroll") for (int t = 0; t < 4; ++t) { \
      kf0[t] = *(const bf16x8*)(kb_ + offs0[t]); \
      kf1[t] = *(const bf16x8*)(kb_ + offs1[t]); \
      vf0[t] = *(const bf16x8*)(vb_ + offs0[t]); \
      vf1[t] = *(const bf16x8*)(vb_ + offs1[t]); } \
    asm volatile("s_waitcnt lgkmcnt(0)" ::: "memory"); \
    __builtin_amdgcn_sched_barrier(0); \
    __builtin_amdgcn_s_barrier();            /* all waves done reading buf */ \
    __builtin_amdgcn_sched_barrier(0); \
    if (DOSTAGE) { STAGE(B); } \
    __builtin_amdgcn_sched_barrier(0); \
    __builtin_amdgcn_s_setprio(1); \
    f32x16 st0 = __builtin_amdgcn_mfma_f32_32x32x16_bf16(kf0[0], qf[0], z16, 0, 0, 0); \
    f32x16 st1 = __builtin_amdgcn_mfma_f32_32x32x16_bf16(kf1[0], qf[0], z16, 0, 0, 0); \
    _Pragma("unroll") for (int t = 1; t < 4; ++t) { \
      st0 = __builtin_amdgcn_mfma_f32_32x32x16_bf16(kf0[t], qf[t], st0, 0, 0, 0); \
      st1 = __builtin_amdgcn_mfma_f32_32x32x16_bf16(kf1[t], qf[t], st1, 0, 0, 0); } \
    __builtin_amdgcn_s_setprio(0); \
    float pm = fmaxf(fmaxf(st0[0], st0[1]), st0[2]); \
    _Pragma("unroll") for (int r = 3; r < 15; r += 3) \
      pm = fmaxf(fmaxf(fmaxf(pm, st0[r]), st0[r+1]), st0[r+2]); \
    pm = fmaxf(pm, st0[15]); \
    _Pragma("unroll") for (int r = 0; r < 15; r += 3) \
      pm = fmaxf(fmaxf(fmaxf(pm, st1[r]), st1[r+1]), st1[r+2]); \
    pm = fmaxf(pm, st1[15]); \
    pm = fmaxf(pm, __shfl_xor(pm, 32)); \
    if (__any(pm > m + THR)) { \
      float mn = fmaxf(m, pm); \
      float scl = exp2f(m - mn); \
      m = mn; \
      _Pragma("unroll") for (int r = 0; r < 16; ++r) { \
        int crow = (r & 3) + 8*(r >> 2) + 4*hi; \
        float sr = __int_as_float( \
            __builtin_amdgcn_ds_bpermute(crow << 2, __float_as_int(scl))); \
        o0[r] *= sr; o1[r] *= sr; lacc[r] *= sr; } } \
    _Pragma("unroll") for (int r = 0; r < 16; ++r) st0[r] = exp2f(st0[r] - m); \
    _Pragma("unroll") for (int r = 0; r < 16; ++r) st1[r] = exp2f(st1[r] - m); \
    bf16x8 pa[4]; \
    _Pragma("unroll") for (int ks = 0; ks < 2; ++ks) { \
      const f32x16& s_ = ks ? st1 : st0; \
      unsigned X[8]; \
      _Pragma("unroll") for (int w = 0; w < 8; ++w) { \
        float lo_f = s_[2*w], hi_f = s_[2*w + 1]; \
        asm("v_cvt_pk_bf16_f32 %0, %1, %2" : "=v"(X[w]) : "v"(lo_f), "v"(hi_f)); } \
      asm volatile("v_permlane32_swap_b32 %0, %1" : "+v"(X[0]), "+v"(X[2])); \
      asm volatile("v_permlane32_swap_b32 %0, %1" : "+v"(X[1]), "+v"(X[3])); \
      asm volatile("v_permlane32_swap_b32 %0, %1" : "+v"(X[4]), "+v"(X[6])); \
      asm volatile("v_permlane32_swap_b32 %0, %1" : "+v"(X[5]), "+v"(X[7])); \
      union { u32x4 u; bf16x8 b; } cva, cvb; \
      cva.u = (u32x4){X[0], X[1], X[2], X[3]}; \
      cvb.u = (u32x4){X[4], X[5], X[6], X[7]}; \
      pa[2*ks]   = cva.b; \
      pa[2*ks+1] = cvb.b; } \
    __builtin_amdgcn_s_setprio(1); \
    _Pragma("unroll") for (int t = 0; t < 4; ++t) { \
      o0 = __builtin_amdgcn_mfma_f32_32x32x16_bf16(pa[t], vf0[t], o0, 0, 0, 0); \
      o1 = __builtin_amdgcn_mfma_f32_32x32x16_bf16(pa[t], vf1[t], o1, 0, 0, 0); } \
    _Pragma("unroll") for (int t = 0; t < 4; ++t) \
      lacc = __builtin_amdgcn_mfma_f32_32x32x16_bf16(pa[t], onesf, lacc, 0, 0, 0); \
    __builtin_amdgcn_s_setprio(0); \
  } while (0)

  STAGE(0);                                   // tile 0 -> buf0 (4 loads)
  STAGE(1);                                   // tile 1 -> buf1 (8 in flight)

#pragma unroll 1
  for (int kv = 0; kv < NT - 2; kv += 2) {
    TILE(0, "vmcnt(4)", 1);                   // compute tile kv,   stage kv+2
    TILE(1, "vmcnt(4)", 1);                   // compute tile kv+1, stage kv+3
  }
  TILE(0, "vmcnt(4)", 0);                     // tile NT-2 (NT-1 still in flight)
  TILE(1, "vmcnt(0)", 0);                     // tile NT-1

#undef STAGE
#undef TILE

  // ---- epilogue: O /= l (l already in C layout via MFMA row-sum) ----
  const int b = bh >> 4, h = bh & 15;
#pragma unroll
  for (int r = 0; r < 16; ++r) {
    int crow = (r & 3) + 8*(r >> 2) + 4*hi;
    float lr = 1.0f / lacc[r];
    int s = qb + crow;
    u16* row = ctx + ((size_t)(b*SEQ + s))*D_EMB + h*64;
    row[lo5]      = f2b(o0[r] * lr);
    row[32 + lo5] = f2b(o1[r] * lr);
  }
}

// ---------------- output projection + bias + residual ----------------
__global__ __launch_bounds__(256) void gemm_out(
    const u16* __restrict__ ctx, const u16* __restrict__ Wot,
    const float* __restrict__ bo, const float* __restrict__ resid,
    float* __restrict__ preln) {
  __shared__ u16 lds_a[128*64];
  __shared__ u16 lds_b[128*64];
  int tid = threadIdx.x, wid = tid >> 6, lane = tid & 63;
  int wr = wid >> 1, wc = wid & 1;
  int bm = blockIdx.y, bn = blockIdx.x;
  f32x4 acc[4][4];
#pragma unroll
  for (int i = 0; i < 4; ++i)
#pragma unroll
    for (int j = 0; j < 4; ++j) acc[i][j] = (f32x4){0.f,0.f,0.f,0.f};
  gemm_loop(ctx, Wot, lds_a, lds_b, bm, bn, wid, lane, wr, wc, acc);
  int g = lane >> 4, c = lane & 15;
#pragma unroll
  for (int mb = 0; mb < 4; ++mb) {
    int row0 = bm*128 + wr*64 + mb*16 + g*4;
#pragma unroll
    for (int nb = 0; nb < 4; ++nb) {
      int col = bn*128 + wc*64 + nb*16 + c;
      float bsv = bo[col];
#pragma unroll
      for (int r = 0; r < 4; ++r) {
        int m = row0 + r;
        preln[(size_t)m*D_EMB + col] = acc[mb][nb][r] + bsv + resid[(size_t)m*D_EMB + col];
      }
    }
  }
}

// ---------------- LayerNorm over rows of 1024 ----------------
__global__ __launch_bounds__(256) void ln_k(
    const float* __restrict__ preln, const float* __restrict__ gamma,
    const float* __restrict__ beta, float* __restrict__ out) {
  int row = blockIdx.x, tid = threadIdx.x;
  float4 x = ((const float4*)(preln + (size_t)row*D_EMB))[tid];
  float s  = x.x + x.y + x.z + x.w;
  float ss = x.x*x.x + x.y*x.y + x.z*x.z + x.w*x.w;
#pragma unroll
  for (int off = 32; off; off >>= 1) {
    s  += __shfl_xor(s, off);
    ss += __shfl_xor(ss, off);
  }
  __shared__ float red_s[4], red_ss[4];
  int wid = tid >> 6, lane = tid & 63;
  if (lane == 0) { red_s[wid] = s; red_ss[wid] = ss; }
  __syncthreads();
  s  = red_s[0] + red_s[1] + red_s[2] + red_s[3];
  ss = red_ss[0] + red_ss[1] + red_ss[2] + red_ss[3];
  float mu = s * (1.0f/1024.0f);
  float var = ss * (1.0f/1024.0f) - mu*mu;
  float rstd = rsqrtf(var + 1e-6f);
  float4 gm = ((const float4*)gamma)[tid];
  float4 bt = ((const float4*)beta)[tid];
  float4 y;
  y.x = (x.x - mu)*rstd*gm.x + bt.x;
  y.y = (x.y - mu)*rstd*gm.y + bt.y;
  y.z = (x.z - mu)*rstd*gm.z + bt.z;
  y.w = (x.w - mu)*rstd*gm.w + bt.w;
  ((float4*)(out + (size_t)row*D_EMB))[tid] = y;
}

extern "C" void kernel_launch(void* const* d_in, const int* in_sizes, int n_in,
                              void* d_out, int out_size, void* d_ws, size_t ws_size,
                              hipStream_t stream) {
  const float* v_in  = (const float*)d_in[0];
  const float* k_in  = (const float*)d_in[1];
  const float* q_in  = (const float*)d_in[2];
  const float* Wv    = (const float*)d_in[3];
  const float* bv    = (const float*)d_in[4];
  const float* Wk    = (const float*)d_in[5];
  const float* bk    = (const float*)d_in[6];
  const float* Wq    = (const float*)d_in[7];
  const float* bq    = (const float*)d_in[8];
  const float* Wo    = (const float*)d_in[9];
  const float* bo    = (const float*)d_in[10];
  const float* gamma = (const float*)d_in[11];
  const float* beta  = (const float*)d_in[12];
  char* ws = (char*)d_ws;

  const size_t TOKB = (size_t)MTOT * D_EMB * 2;   // bf16 activation (8 MB)
  const size_t WB   = (size_t)D_EMB * D_EMB * 2;  // bf16 weight (2 MB)
  size_t o_qb = 0;
  size_t o_kb = o_qb + TOKB;
  size_t o_vb = o_kb + TOKB;
  size_t o_wq = o_vb + TOKB;
  size_t o_wk = o_wq + WB;
  size_t o_wv = o_wk + WB;
  size_t o_wo = o_wv + WB;
  size_t o_Qh = o_wo + WB;
  size_t o_Kh = o_Qh + TOKB;
  size_t o_Vt = o_Kh + TOKB;
  size_t o_cx = o_Vt + TOKB;
  // preln (fp32, 16 MB) aliases qb+kb, which are dead after gemm_qkv

  u16* qb  = (u16*)(ws + o_qb);
  u16* kb  = (u16*)(ws + o_kb);
  u16* vb  = (u16*)(ws + o_vb);
  u16* wqt = (u16*)(ws + o_wq);
  u16* wkt = (u16*)(ws + o_wk);
  u16* wvt = (u16*)(ws + o_wv);
  u16* wot = (u16*)(ws + o_wo);
  u16* Qh  = (u16*)(ws + o_Qh);
  u16* Kh  = (u16*)(ws + o_Kh);
  u16* Vt  = (u16*)(ws + o_Vt);
  u16* cx  = (u16*)(ws + o_cx);
  float* preln = (float*)(ws + 0);

  convert_qkv<<<4096, 256, 0, stream>>>(v_in, k_in, q_in, vb, kb, qb);
  transpose_w<<<dim3(32, 32, 4), dim3(32, 8), 0, stream>>>(Wv, Wk, Wq, Wo, wvt, wkt, wqt, wot);
  gemm_qkv<<<dim3(8, 32, 3), 256, 0, stream>>>(vb, kb, qb, wvt, wkt, wqt, bv, bk, bq, Vt, Kh, Qh);
  attn_k<<<512, 256, 0, stream>>>(Qh, Kh, Vt, cx);
  gemm_out<<<dim3(8, 32), 256, 0, stream>>>(cx, wot, bo, q_in, preln);
  ln_k<<<4096, 256, 0, stream>>>(preln, gamma, beta, (float*)d_out);
}